// Round 1
// baseline (1111.862 us; speedup 1.0000x reference)
//
#include <hip/hip_runtime.h>
#include <hip/hip_bf16.h>

typedef unsigned short u16;
typedef __attribute__((ext_vector_type(8))) short bf16x8;
typedef __attribute__((ext_vector_type(4))) float f32x4;
typedef __attribute__((ext_vector_type(4))) float vfloat4;
typedef __attribute__((ext_vector_type(4))) unsigned short ushort4v;
typedef __attribute__((ext_vector_type(8))) unsigned short ushort8v;

#define DEV __device__ __forceinline__

DEV u16 f2bf(float f) {
    union { float f; unsigned u; } v; v.f = f;
    unsigned r = v.u + 0x7FFFu + ((v.u >> 16) & 1u);
    return (u16)(r >> 16);
}

static constexpr int KDIM = 1024;   // embed
static constexpr int NROW = 65536;  // B*S

// ---------------- Pass 1: Y = X @ W^T + b, bf16 output ----------------
// X: [65536,1024] f32, W: [1024,1024] f32 (row n holds W[n][k]), bias [1024]
// tile 128x128, BK=64, 4 waves of 64x64 (4x4 frags of 16x16x32)
__global__ __launch_bounds__(256)
void proj_gemm(const float* __restrict__ X, const float* __restrict__ W,
               const float* __restrict__ bias, u16* __restrict__ Y)
{
    __shared__ u16 As[128 * 64];  // [row][k], XOR-swizzled
    __shared__ u16 Bs[128 * 64];  // [n][k],   XOR-swizzled

    int bx = blockIdx.x;                 // 0..4095
    int wg = (bx & 7) * 512 + (bx >> 3); // XCD-chunked swizzle (4096 % 8 == 0)
    int bm = wg >> 3;                    // 0..511
    int bn = wg & 7;                     // 0..7

    int tid  = threadIdx.x;
    int lane = tid & 63;
    int wid  = tid >> 6;
    int wrow = (wid >> 1) * 64;
    int wcol = (wid & 1) * 64;
    int l15 = lane & 15;
    int l4  = lane >> 4;

    int srow = tid >> 4;        // 0..15
    int scol = (tid & 15) * 4;  // 0..60 step 4

    const float* Xp = X + (size_t)bm * 128 * KDIM;
    const float* Wp = W + (size_t)bn * 128 * KDIM;

    f32x4 acc[4][4] = {};

    for (int k0 = 0; k0 < KDIM; k0 += 64) {
        __syncthreads();
#pragma unroll
        for (int r = 0; r < 8; ++r) {
            int row = r * 16 + srow;
            vfloat4 a = *(const vfloat4*)(Xp + (size_t)row * KDIM + k0 + scol);
            vfloat4 b = *(const vfloat4*)(Wp + (size_t)row * KDIM + k0 + scol);
            ushort4v ap, bp;
#pragma unroll
            for (int j = 0; j < 4; ++j) { ap[j] = f2bf(a[j]); bp[j] = f2bf(b[j]); }
            unsigned off = (unsigned)(row * 128 + scol * 2) ^ (unsigned)((row & 7) << 4);
            *(ushort4v*)((char*)As + off) = ap;
            *(ushort4v*)((char*)Bs + off) = bp;
        }
        __syncthreads();
#pragma unroll
        for (int kk = 0; kk < 2; ++kk) {
            bf16x8 af[4], bfr[4];
#pragma unroll
            for (int mi = 0; mi < 4; ++mi) {
                int row = wrow + mi * 16 + l15;
                unsigned off = (unsigned)(row * 128 + kk * 64 + l4 * 16) ^ (unsigned)((row & 7) << 4);
                af[mi] = *(const bf16x8*)((char*)As + off);
            }
#pragma unroll
            for (int ni = 0; ni < 4; ++ni) {
                int row = wcol + ni * 16 + l15;
                unsigned off = (unsigned)(row * 128 + kk * 64 + l4 * 16) ^ (unsigned)((row & 7) << 4);
                bfr[ni] = *(const bf16x8*)((char*)Bs + off);
            }
#pragma unroll
            for (int mi = 0; mi < 4; ++mi)
#pragma unroll
                for (int ni = 0; ni < 4; ++ni)
                    acc[mi][ni] = __builtin_amdgcn_mfma_f32_16x16x32_bf16(
                        af[mi], bfr[ni], acc[mi][ni], 0, 0, 0);
        }
    }

    // epilogue: + bias, bf16 store. D-frag: col = l15, rows = l4*4 + r
#pragma unroll
    for (int ni = 0; ni < 4; ++ni) {
        int col = bn * 128 + wcol + ni * 16 + l15;
        float bv = bias[col];
#pragma unroll
        for (int mi = 0; mi < 4; ++mi) {
            int row0 = bm * 128 + wrow + mi * 16 + l4 * 4;
#pragma unroll
            for (int r = 0; r < 4; ++r)
                Y[(size_t)(row0 + r) * KDIM + col] = f2bf(acc[mi][ni][r] + bv);
        }
    }
}

// ---------------- Pass 2: grouped attention ----------------
// block = (group g of 128 rows, head h). Q/K/V bf16 [65536][1024] in ws.
// Swapped QK^T: St = mfma(K, Q) -> St[key][q]; softmax per q in registers.
__global__ __launch_bounds__(256)
void attn_kernel(const u16* __restrict__ Qg, const u16* __restrict__ Kg,
                 const u16* __restrict__ Vg, float* __restrict__ Out)
{
    __shared__ u16 Qs[128 * 64];     // [q][d] swizzled
    __shared__ u16 KVs[64 * 136];    // union: Ks [128][64] swizzled (8192) / Vt [64][136]
    __shared__ u16 Ps[128 * 136];    // [q][k], row stride 136 (272B, 16B aligned)

    int g = blockIdx.x >> 4;
    int h = blockIdx.x & 15;

    int tid  = threadIdx.x;
    int lane = tid & 63;
    int wid  = tid >> 6;
    int l15 = lane & 15, l4 = lane >> 4;
    int qbase = wid * 32;

    size_t rowbase = (size_t)g * 128 * 1024 + (size_t)h * 64;

    // stage Q and K: [128 rows][64 cols], XOR swizzle ((row&7)<<4)
    {
        int r  = tid >> 1;
        int c0 = (tid & 1) * 32;
        const u16* qsrc = Qg + rowbase + (size_t)r * 1024 + c0;
        const u16* ksrc = Kg + rowbase + (size_t)r * 1024 + c0;
#pragma unroll
        for (int i = 0; i < 4; ++i) {
            ushort8v qv = *(const ushort8v*)(qsrc + i * 8);
            ushort8v kv = *(const ushort8v*)(ksrc + i * 8);
            unsigned off = (unsigned)(r * 128 + (c0 + i * 8) * 2) ^ (unsigned)((r & 7) << 4);
            *(ushort8v*)((char*)Qs + off) = qv;
            *(ushort8v*)((char*)KVs + off) = kv;
        }
    }
    __syncthreads();

    // QK^T: wave handles q in [qbase, qbase+32)
    f32x4 st[8][2] = {};
#pragma unroll
    for (int kk = 0; kk < 2; ++kk) {
        bf16x8 kf[8];
#pragma unroll
        for (int mi = 0; mi < 8; ++mi) {
            int row = mi * 16 + l15;
            unsigned off = (unsigned)(row * 128 + kk * 64 + l4 * 16) ^ (unsigned)((row & 7) << 4);
            kf[mi] = *(const bf16x8*)((char*)KVs + off);
        }
#pragma unroll
        for (int qi = 0; qi < 2; ++qi) {
            int row = qbase + qi * 16 + l15;
            unsigned off = (unsigned)(row * 128 + kk * 64 + l4 * 16) ^ (unsigned)((row & 7) << 4);
            bf16x8 qf = *(const bf16x8*)((char*)Qs + off);
#pragma unroll
            for (int mi = 0; mi < 8; ++mi)
                st[mi][qi] = __builtin_amdgcn_mfma_f32_16x16x32_bf16(kf[mi], qf, st[mi][qi], 0, 0, 0);
        }
    }
    __syncthreads();  // Ks reads done -> KVs reusable as Vt

    // stage Vt[d][k] (transpose of V tile), row stride 136
    {
        int r  = tid >> 1;           // key row
        int c0 = (tid & 1) * 32;     // d col
        const u16* vsrc = Vg + rowbase + (size_t)r * 1024 + c0;
#pragma unroll
        for (int i = 0; i < 4; ++i) {
            ushort8v vv = *(const ushort8v*)(vsrc + i * 8);
#pragma unroll
            for (int e = 0; e < 8; ++e)
                KVs[(c0 + i * 8 + e) * 136 + r] = vv[e];
        }
    }

    // softmax in registers; lane's q col = l15, key = mi*16 + l4*4 + r
    const float cexp = 0.125f * 1.44269504088896f;  // log2(e)/sqrt(64)
#pragma unroll
    for (int qi = 0; qi < 2; ++qi) {
        float m = -3.0e38f;
#pragma unroll
        for (int mi = 0; mi < 8; ++mi)
#pragma unroll
            for (int r = 0; r < 4; ++r) m = fmaxf(m, st[mi][qi][r]);
        m = fmaxf(m, __shfl_xor(m, 16));
        m = fmaxf(m, __shfl_xor(m, 32));
        float s = 0.f;
#pragma unroll
        for (int mi = 0; mi < 8; ++mi)
#pragma unroll
            for (int r = 0; r < 4; ++r) {
                float p = exp2f((st[mi][qi][r] - m) * cexp);
                st[mi][qi][r] = p;
                s += p;
            }
        s += __shfl_xor(s, 16);
        s += __shfl_xor(s, 32);
        float inv = 1.0f / s;
        int q = qbase + qi * 16 + l15;
#pragma unroll
        for (int mi = 0; mi < 8; ++mi) {
            ushort4v pp;
#pragma unroll
            for (int r = 0; r < 4; ++r) pp[r] = f2bf(st[mi][qi][r] * inv);
            *(ushort4v*)((char*)Ps + (unsigned)(q * 272 + mi * 32 + l4 * 8)) = pp;
        }
    }
    __syncthreads();

    // O = P @ V. wave: q rows [qbase, qbase+32) x d 0..63
    f32x4 o[2][4] = {};
#pragma unroll
    for (int kk = 0; kk < 4; ++kk) {
        bf16x8 pa[2];
#pragma unroll
        for (int mf = 0; mf < 2; ++mf) {
            int q = qbase + mf * 16 + l15;
            pa[mf] = *(const bf16x8*)((char*)Ps + (unsigned)(q * 272 + kk * 64 + l4 * 16));
        }
#pragma unroll
        for (int nf = 0; nf < 4; ++nf) {
            int d = nf * 16 + l15;
            bf16x8 vb = *(const bf16x8*)((char*)KVs + (unsigned)(d * 272 + kk * 64 + l4 * 16));
#pragma unroll
            for (int mf = 0; mf < 2; ++mf)
                o[mf][nf] = __builtin_amdgcn_mfma_f32_16x16x32_bf16(pa[mf], vb, o[mf][nf], 0, 0, 0);
        }
    }

#pragma unroll
    for (int mf = 0; mf < 2; ++mf)
#pragma unroll
        for (int nf = 0; nf < 4; ++nf) {
            int d  = nf * 16 + l15;
            int q0 = qbase + mf * 16 + l4 * 4;
#pragma unroll
            for (int r = 0; r < 4; ++r)
                Out[(size_t)(g * 128 + q0 + r) * 1024 + h * 64 + d] = o[mf][nf][r];
        }
}

extern "C" void kernel_launch(void* const* d_in, const int* in_sizes, int n_in,
                              void* d_out, int out_size, void* d_ws, size_t ws_size,
                              hipStream_t stream)
{
    const float* Xq = (const float*)d_in[0];
    const float* Xk = (const float*)d_in[1];
    const float* Xv = (const float*)d_in[2];
    const float* Wq = (const float*)d_in[3];
    const float* bq = (const float*)d_in[4];
    const float* Wk = (const float*)d_in[5];
    const float* bk = (const float*)d_in[6];
    const float* Wv = (const float*)d_in[7];
    const float* bv = (const float*)d_in[8];

    u16* Qw = (u16*)d_ws;
    u16* Kw = Qw + (size_t)NROW * KDIM;
    u16* Vw = Kw + (size_t)NROW * KDIM;

    proj_gemm<<<dim3(4096), dim3(256), 0, stream>>>(Xq, Wq, bq, Qw);
    proj_gemm<<<dim3(4096), dim3(256), 0, stream>>>(Xk, Wk, bk, Kw);
    proj_gemm<<<dim3(4096), dim3(256), 0, stream>>>(Xv, Wv, bv, Vw);

    attn_kernel<<<dim3(512 * 16), dim3(256), 0, stream>>>(Qw, Kw, Vw, (float*)d_out);
}

// Round 2
// 1087.049 us; speedup vs baseline: 1.0228x; 1.0228x over previous
//
#include <hip/hip_runtime.h>
#include <hip/hip_bf16.h>

typedef unsigned short u16;
typedef __attribute__((ext_vector_type(8))) short bf16x8;
typedef __attribute__((ext_vector_type(4))) float f32x4;
typedef __attribute__((ext_vector_type(4))) float vfloat4;
typedef __attribute__((ext_vector_type(4))) unsigned short ushort4v;
typedef __attribute__((ext_vector_type(8))) unsigned short ushort8v;

#define DEV __device__ __forceinline__
#define AS1 __attribute__((address_space(1)))
#define AS3 __attribute__((address_space(3)))

DEV u16 f2bf(float f) {
    union { float f; unsigned u; } v; v.f = f;
    unsigned r = v.u + 0x7FFFu + ((v.u >> 16) & 1u);
    return (u16)(r >> 16);
}

DEV void gload_lds16(const void* g, void* l) {
    __builtin_amdgcn_global_load_lds((const AS1 unsigned int*)g,
                                     (AS3 unsigned int*)l, 16, 0, 0);
}

static constexpr int KDIM = 1024;   // embed
static constexpr int NROW = 65536;  // B*S

// ---------------- fp32 -> bf16 convert (memory-bound) ----------------
__global__ __launch_bounds__(256)
void cvt_f32_bf16(const float* __restrict__ src, u16* __restrict__ dst, unsigned n8)
{
    unsigned stride = gridDim.x * blockDim.x;
    for (unsigned i = blockIdx.x * blockDim.x + threadIdx.x; i < n8; i += stride) {
        size_t base = (size_t)i * 8;
        vfloat4 a = *(const vfloat4*)(src + base);
        vfloat4 b = *(const vfloat4*)(src + base + 4);
        ushort8v o;
#pragma unroll
        for (int j = 0; j < 4; ++j) { o[j] = f2bf(a[j]); o[j + 4] = f2bf(b[j]); }
        *(ushort8v*)(dst + base) = o;
    }
}

// ---------------- Pass 1 (plan A): Y = Xb @ Wb^T + b, all bf16, m97 structure --
// Xb: [65536,1024] bf16, Wb: [1024,1024] bf16 row-major [n][k], bias fp32
// tile 128x128, BK=64, 4 waves of 64x64 (4x4 frags of 16x16x32), global_load_lds
__global__ __launch_bounds__(256)
void proj_gemm_bf16(const u16* __restrict__ X, const u16* __restrict__ W,
                    const float* __restrict__ bias, u16* __restrict__ Y)
{
    __shared__ u16 As[128 * 64];   // [row][k] linear (gload_lds dest must be linear)
    __shared__ u16 Bs[128 * 64];

    int bx = blockIdx.x;                 // 0..4095
    int wg = (bx & 7) * 512 + (bx >> 3); // XCD-chunked swizzle (4096 % 8 == 0)
    int bm = wg >> 3;                    // 0..511
    int bn = wg & 7;                     // 0..7

    int tid  = threadIdx.x;
    int lane = tid & 63;
    int wid  = tid >> 6;
    int wrow = (wid >> 1) * 64;
    int wcol = (wid & 1) * 64;
    int l15 = lane & 15;
    int l4  = lane >> 4;

    const u16* Xp = X + (size_t)bm * 128 * KDIM;
    const u16* Wp = W + (size_t)bn * 128 * KDIM;

    // staging geometry: wave w stages rows [w*32, w*32+32) in 4 issues of 8 rows
    int srow = wid * 32 + (lane >> 3);   // + c*8
    int scol = (lane & 7) * 8;           // 8 bf16 = 16B per lane

    f32x4 acc[4][4] = {};

    for (int k0 = 0; k0 < KDIM; k0 += 64) {
        __syncthreads();   // prior ds_reads done before overwrite
#pragma unroll
        for (int c = 0; c < 4; ++c) {
            int row = srow + c * 8;
            const u16* ga = Xp + (size_t)row * KDIM + k0 + scol;
            const u16* gb = Wp + (size_t)row * KDIM + k0 + scol;
            gload_lds16(ga, &As[(wid * 32 + c * 8) * 64]);
            gload_lds16(gb, &Bs[(wid * 32 + c * 8) * 64]);
        }
        __syncthreads();   // compiler drains vmcnt before barrier -> LDS ready
#pragma unroll
        for (int kk = 0; kk < 2; ++kk) {
            bf16x8 af[4], bfr[4];
#pragma unroll
            for (int mi = 0; mi < 4; ++mi)
                af[mi] = *(const bf16x8*)&As[(wrow + mi * 16 + l15) * 64 + kk * 32 + l4 * 8];
#pragma unroll
            for (int ni = 0; ni < 4; ++ni)
                bfr[ni] = *(const bf16x8*)&Bs[(wcol + ni * 16 + l15) * 64 + kk * 32 + l4 * 8];
#pragma unroll
            for (int mi = 0; mi < 4; ++mi)
#pragma unroll
                for (int ni = 0; ni < 4; ++ni)
                    acc[mi][ni] = __builtin_amdgcn_mfma_f32_16x16x32_bf16(
                        af[mi], bfr[ni], acc[mi][ni], 0, 0, 0);
        }
    }

    // epilogue: + bias, bf16 store. D-frag: col = l15, rows = l4*4 + r
#pragma unroll
    for (int ni = 0; ni < 4; ++ni) {
        int col = bn * 128 + wcol + ni * 16 + l15;
        float bv = bias[col];
#pragma unroll
        for (int mi = 0; mi < 4; ++mi) {
            int row0 = bm * 128 + wrow + mi * 16 + l4 * 4;
#pragma unroll
            for (int r = 0; r < 4; ++r)
                Y[(size_t)(row0 + r) * KDIM + col] = f2bf(acc[mi][ni][r] + bv);
        }
    }
}

// ---------------- Pass 1 (plan B fallback): fp32 in, convert in-loop ----------
__global__ __launch_bounds__(256)
void proj_gemm(const float* __restrict__ X, const float* __restrict__ W,
               const float* __restrict__ bias, u16* __restrict__ Y)
{
    __shared__ u16 As[128 * 64];
    __shared__ u16 Bs[128 * 64];

    int bx = blockIdx.x;
    int wg = (bx & 7) * 512 + (bx >> 3);
    int bm = wg >> 3;
    int bn = wg & 7;

    int tid  = threadIdx.x;
    int lane = tid & 63;
    int wid  = tid >> 6;
    int wrow = (wid >> 1) * 64;
    int wcol = (wid & 1) * 64;
    int l15 = lane & 15;
    int l4  = lane >> 4;

    int srow = tid >> 4;
    int scol = (tid & 15) * 4;

    const float* Xp = X + (size_t)bm * 128 * KDIM;
    const float* Wp = W + (size_t)bn * 128 * KDIM;

    f32x4 acc[4][4] = {};

    for (int k0 = 0; k0 < KDIM; k0 += 64) {
        __syncthreads();
#pragma unroll
        for (int r = 0; r < 8; ++r) {
            int row = r * 16 + srow;
            vfloat4 a = *(const vfloat4*)(Xp + (size_t)row * KDIM + k0 + scol);
            vfloat4 b = *(const vfloat4*)(Wp + (size_t)row * KDIM + k0 + scol);
            ushort4v ap, bp;
#pragma unroll
            for (int j = 0; j < 4; ++j) { ap[j] = f2bf(a[j]); bp[j] = f2bf(b[j]); }
            unsigned off = (unsigned)(row * 128 + scol * 2) ^ (unsigned)((row & 7) << 4);
            *(ushort4v*)((char*)As + off) = ap;
            *(ushort4v*)((char*)Bs + off) = bp;
        }
        __syncthreads();
#pragma unroll
        for (int kk = 0; kk < 2; ++kk) {
            bf16x8 af[4], bfr[4];
#pragma unroll
            for (int mi = 0; mi < 4; ++mi) {
                int row = wrow + mi * 16 + l15;
                unsigned off = (unsigned)(row * 128 + kk * 64 + l4 * 16) ^ (unsigned)((row & 7) << 4);
                af[mi] = *(const bf16x8*)((char*)As + off);
            }
#pragma unroll
            for (int ni = 0; ni < 4; ++ni) {
                int row = wcol + ni * 16 + l15;
                unsigned off = (unsigned)(row * 128 + kk * 64 + l4 * 16) ^ (unsigned)((row & 7) << 4);
                bfr[ni] = *(const bf16x8*)((char*)Bs + off);
            }
#pragma unroll
            for (int mi = 0; mi < 4; ++mi)
#pragma unroll
                for (int ni = 0; ni < 4; ++ni)
                    acc[mi][ni] = __builtin_amdgcn_mfma_f32_16x16x32_bf16(
                        af[mi], bfr[ni], acc[mi][ni], 0, 0, 0);
        }
    }

#pragma unroll
    for (int ni = 0; ni < 4; ++ni) {
        int col = bn * 128 + wcol + ni * 16 + l15;
        float bv = bias[col];
#pragma unroll
        for (int mi = 0; mi < 4; ++mi) {
            int row0 = bm * 128 + wrow + mi * 16 + l4 * 4;
#pragma unroll
            for (int r = 0; r < 4; ++r)
                Y[(size_t)(row0 + r) * KDIM + col] = f2bf(acc[mi][ni][r] + bv);
        }
    }
}

// ---------------- Pass 2: grouped attention ----------------
__global__ __launch_bounds__(256)
void attn_kernel(const u16* __restrict__ Qg, const u16* __restrict__ Kg,
                 const u16* __restrict__ Vg, float* __restrict__ Out)
{
    __shared__ u16 Qs[128 * 64];     // [q][d] swizzled
    __shared__ u16 KVs[64 * 136];    // union: Ks [128][64] swizzled / Vt [64][136]
    __shared__ u16 Ps[128 * 136];    // [q][k], row stride 136

    int g = blockIdx.x >> 4;
    int h = blockIdx.x & 15;

    int tid  = threadIdx.x;
    int lane = tid & 63;
    int wid  = tid >> 6;
    int l15 = lane & 15, l4 = lane >> 4;
    int qbase = wid * 32;

    size_t rowbase = (size_t)g * 128 * 1024 + (size_t)h * 64;

    {
        int r  = tid >> 1;
        int c0 = (tid & 1) * 32;
        const u16* qsrc = Qg + rowbase + (size_t)r * 1024 + c0;
        const u16* ksrc = Kg + rowbase + (size_t)r * 1024 + c0;
#pragma unroll
        for (int i = 0; i < 4; ++i) {
            ushort8v qv = *(const ushort8v*)(qsrc + i * 8);
            ushort8v kv = *(const ushort8v*)(ksrc + i * 8);
            unsigned off = (unsigned)(r * 128 + (c0 + i * 8) * 2) ^ (unsigned)((r & 7) << 4);
            *(ushort8v*)((char*)Qs + off) = qv;
            *(ushort8v*)((char*)KVs + off) = kv;
        }
    }
    __syncthreads();

    f32x4 st[8][2] = {};
#pragma unroll
    for (int kk = 0; kk < 2; ++kk) {
        bf16x8 kf[8];
#pragma unroll
        for (int mi = 0; mi < 8; ++mi) {
            int row = mi * 16 + l15;
            unsigned off = (unsigned)(row * 128 + kk * 64 + l4 * 16) ^ (unsigned)((row & 7) << 4);
            kf[mi] = *(const bf16x8*)((char*)KVs + off);
        }
#pragma unroll
        for (int qi = 0; qi < 2; ++qi) {
            int row = qbase + qi * 16 + l15;
            unsigned off = (unsigned)(row * 128 + kk * 64 + l4 * 16) ^ (unsigned)((row & 7) << 4);
            bf16x8 qf = *(const bf16x8*)((char*)Qs + off);
#pragma unroll
            for (int mi = 0; mi < 8; ++mi)
                st[mi][qi] = __builtin_amdgcn_mfma_f32_16x16x32_bf16(kf[mi], qf, st[mi][qi], 0, 0, 0);
        }
    }
    __syncthreads();

    {
        int r  = tid >> 1;
        int c0 = (tid & 1) * 32;
        const u16* vsrc = Vg + rowbase + (size_t)r * 1024 + c0;
#pragma unroll
        for (int i = 0; i < 4; ++i) {
            ushort8v vv = *(const ushort8v*)(vsrc + i * 8);
#pragma unroll
            for (int e = 0; e < 8; ++e)
                KVs[(c0 + i * 8 + e) * 136 + r] = vv[e];
        }
    }

    const float cexp = 0.125f * 1.44269504088896f;
#pragma unroll
    for (int qi = 0; qi < 2; ++qi) {
        float m = -3.0e38f;
#pragma unroll
        for (int mi = 0; mi < 8; ++mi)
#pragma unroll
            for (int r = 0; r < 4; ++r) m = fmaxf(m, st[mi][qi][r]);
        m = fmaxf(m, __shfl_xor(m, 16));
        m = fmaxf(m, __shfl_xor(m, 32));
        float s = 0.f;
#pragma unroll
        for (int mi = 0; mi < 8; ++mi)
#pragma unroll
            for (int r = 0; r < 4; ++r) {
                float p = exp2f((st[mi][qi][r] - m) * cexp);
                st[mi][qi][r] = p;
                s += p;
            }
        s += __shfl_xor(s, 16);
        s += __shfl_xor(s, 32);
        float inv = 1.0f / s;
        int q = qbase + qi * 16 + l15;
#pragma unroll
        for (int mi = 0; mi < 8; ++mi) {
            ushort4v pp;
#pragma unroll
            for (int r = 0; r < 4; ++r) pp[r] = f2bf(st[mi][qi][r] * inv);
            *(ushort4v*)((char*)Ps + (unsigned)(q * 272 + mi * 32 + l4 * 8)) = pp;
        }
    }
    __syncthreads();

    f32x4 o[2][4] = {};
#pragma unroll
    for (int kk = 0; kk < 4; ++kk) {
        bf16x8 pa[2];
#pragma unroll
        for (int mf = 0; mf < 2; ++mf) {
            int q = qbase + mf * 16 + l15;
            pa[mf] = *(const bf16x8*)((char*)Ps + (unsigned)(q * 272 + kk * 64 + l4 * 16));
        }
#pragma unroll
        for (int nf = 0; nf < 4; ++nf) {
            int d = nf * 16 + l15;
            bf16x8 vb = *(const bf16x8*)((char*)KVs + (unsigned)(d * 272 + kk * 64 + l4 * 16));
#pragma unroll
            for (int mf = 0; mf < 2; ++mf)
                o[mf][nf] = __builtin_amdgcn_mfma_f32_16x16x32_bf16(pa[mf], vb, o[mf][nf], 0, 0, 0);
        }
    }

#pragma unroll
    for (int mf = 0; mf < 2; ++mf)
#pragma unroll
        for (int nf = 0; nf < 4; ++nf) {
            int d  = nf * 16 + l15;
            int q0 = qbase + mf * 16 + l4 * 4;
#pragma unroll
            for (int r = 0; r < 4; ++r)
                Out[(size_t)(g * 128 + q0 + r) * 1024 + h * 64 + d] = o[mf][nf][r];
        }
}

extern "C" void kernel_launch(void* const* d_in, const int* in_sizes, int n_in,
                              void* d_out, int out_size, void* d_ws, size_t ws_size,
                              hipStream_t stream)
{
    const float* Xq = (const float*)d_in[0];
    const float* Xk = (const float*)d_in[1];
    const float* Xv = (const float*)d_in[2];
    const float* Wq = (const float*)d_in[3];
    const float* bq = (const float*)d_in[4];
    const float* Wk = (const float*)d_in[5];
    const float* bk = (const float*)d_in[6];
    const float* Wv = (const float*)d_in[7];
    const float* bv = (const float*)d_in[8];

    const size_t NE = (size_t)NROW * KDIM;       // 67,108,864
    const size_t WE = (size_t)KDIM * KDIM;       // 1,048,576

    u16* Qw = (u16*)d_ws;
    u16* Kw = Qw + NE;
    u16* Vw = Kw + NE;

    size_t need = NE * 2 * 3 + NE * 2 + WE * 2 * 3;  // QKV + X-stage + 3 W

    if (ws_size >= need) {
        u16* Xb  = Vw + NE;          // shared X staging buffer (reused 3x)
        u16* Wb0 = Xb + NE;
        u16* Wb1 = Wb0 + WE;
        u16* Wb2 = Wb1 + WE;

        cvt_f32_bf16<<<dim3(512),  dim3(256), 0, stream>>>(Wq, Wb0, (unsigned)(WE / 8));
        cvt_f32_bf16<<<dim3(512),  dim3(256), 0, stream>>>(Wk, Wb1, (unsigned)(WE / 8));
        cvt_f32_bf16<<<dim3(512),  dim3(256), 0, stream>>>(Wv, Wb2, (unsigned)(WE / 8));

        cvt_f32_bf16<<<dim3(2048), dim3(256), 0, stream>>>(Xq, Xb, (unsigned)(NE / 8));
        proj_gemm_bf16<<<dim3(4096), dim3(256), 0, stream>>>(Xb, Wb0, bq, Qw);
        cvt_f32_bf16<<<dim3(2048), dim3(256), 0, stream>>>(Xk, Xb, (unsigned)(NE / 8));
        proj_gemm_bf16<<<dim3(4096), dim3(256), 0, stream>>>(Xb, Wb1, bk, Kw);
        cvt_f32_bf16<<<dim3(2048), dim3(256), 0, stream>>>(Xv, Xb, (unsigned)(NE / 8));
        proj_gemm_bf16<<<dim3(4096), dim3(256), 0, stream>>>(Xb, Wb2, bv, Vw);
    } else {
        proj_gemm<<<dim3(4096), dim3(256), 0, stream>>>(Xq, Wq, bq, Qw);
        proj_gemm<<<dim3(4096), dim3(256), 0, stream>>>(Xk, Wk, bk, Kw);
        proj_gemm<<<dim3(4096), dim3(256), 0, stream>>>(Xv, Wv, bv, Vw);
    }

    attn_kernel<<<dim3(512 * 16), dim3(256), 0, stream>>>(Qw, Kw, Vw, (float*)d_out);
}

// Round 3
// 1030.329 us; speedup vs baseline: 1.0791x; 1.0551x over previous
//
#include <hip/hip_runtime.h>
#include <hip/hip_bf16.h>

typedef unsigned short u16;
typedef __attribute__((ext_vector_type(8))) short bf16x8;
typedef __attribute__((ext_vector_type(4))) float f32x4;
typedef __attribute__((ext_vector_type(4))) float vfloat4;
typedef __attribute__((ext_vector_type(4))) unsigned short ushort4v;
typedef __attribute__((ext_vector_type(8))) unsigned short ushort8v;

#define DEV __device__ __forceinline__
#define AS1 __attribute__((address_space(1)))
#define AS3 __attribute__((address_space(3)))

DEV u16 f2bf(float f) {
    union { float f; unsigned u; } v; v.f = f;
    unsigned r = v.u + 0x7FFFu + ((v.u >> 16) & 1u);
    return (u16)(r >> 16);
}

DEV void gload_lds16(const void* g, void* l) {
    __builtin_amdgcn_global_load_lds((const AS1 unsigned int*)g,
                                     (AS3 unsigned int*)l, 16, 0, 0);
}

static constexpr int KDIM = 1024;   // embed
static constexpr int NROW = 65536;  // B*S

// ---------------- fp32 -> bf16 convert (memory-bound) ----------------
__global__ __launch_bounds__(256)
void cvt_f32_bf16(const float* __restrict__ src, u16* __restrict__ dst, unsigned n8)
{
    unsigned stride = gridDim.x * blockDim.x;
    for (unsigned i = blockIdx.x * blockDim.x + threadIdx.x; i < n8; i += stride) {
        size_t base = (size_t)i * 8;
        vfloat4 a = *(const vfloat4*)(src + base);
        vfloat4 b = *(const vfloat4*)(src + base + 4);
        ushort8v o;
#pragma unroll
        for (int j = 0; j < 4; ++j) { o[j] = f2bf(a[j]); o[j + 4] = f2bf(b[j]); }
        *(ushort8v*)(dst + base) = o;
    }
}

// ---------------- Pass 1 (plan A): Y = Xb @ Wb^T + b, all bf16 ----------------
// m97 structure + pre-swizzled global source so LDS holds the XOR-swizzled
// layout (global_load_lds dest must stay linear; swizzle goes on the SOURCE
// address and the READ offset — both-sides-or-neither, rule #21).
__global__ __launch_bounds__(256)
void proj_gemm_bf16(const u16* __restrict__ X, const u16* __restrict__ W,
                    const float* __restrict__ bias, u16* __restrict__ Y)
{
    __shared__ u16 As[128 * 64];
    __shared__ u16 Bs[128 * 64];

    int bx = blockIdx.x;                 // 0..4095
    int wg = (bx & 7) * 512 + (bx >> 3); // XCD-chunked swizzle (4096 % 8 == 0)
    int bm = wg >> 3;                    // 0..511
    int bn = wg & 7;                     // 0..7

    int tid  = threadIdx.x;
    int lane = tid & 63;
    int wid  = tid >> 6;
    int wrow = (wid >> 1) * 64;
    int wcol = (wid & 1) * 64;
    int l15 = lane & 15;
    int l4  = lane >> 4;

    const u16* Xp = X + (size_t)bm * 128 * KDIM;
    const u16* Wp = W + (size_t)bn * 128 * KDIM;

    // staging: wave w stages rows [w*32, w*32+32) in 4 issues of 8 rows.
    // lane l covers (row = l>>3, col16 = l&7) of each 8-row block; the global
    // source col is XOR'd with the row so LDS (linear dest) holds swizzled data.
    int srow8 = lane >> 3;                       // 0..7, == row&7
    int scol  = ((lane & 7) ^ srow8) * 8;        // pre-swizzled source col (bf16 units)
    int srow  = wid * 32 + srow8;                // + c*8

    f32x4 acc[4][4] = {};

    for (int k0 = 0; k0 < KDIM; k0 += 64) {
        __syncthreads();   // prior ds_reads done before overwrite
#pragma unroll
        for (int c = 0; c < 4; ++c) {
            int row = srow + c * 8;
            const u16* ga = Xp + (size_t)row * KDIM + k0 + scol;
            const u16* gb = Wp + (size_t)row * KDIM + k0 + scol;
            gload_lds16(ga, &As[(wid * 32 + c * 8) * 64]);
            gload_lds16(gb, &Bs[(wid * 32 + c * 8) * 64]);
        }
        __syncthreads();   // vmcnt drained before barrier -> LDS ready
#pragma unroll
        for (int kk = 0; kk < 2; ++kk) {
            bf16x8 af[4], bfr[4];
#pragma unroll
            for (int mi = 0; mi < 4; ++mi) {
                int row = wrow + mi * 16 + l15;
                unsigned off = (unsigned)(row * 128 + kk * 64 + l4 * 16) ^ (unsigned)((row & 7) << 4);
                af[mi] = *(const bf16x8*)((char*)As + off);
            }
#pragma unroll
            for (int ni = 0; ni < 4; ++ni) {
                int row = wcol + ni * 16 + l15;
                unsigned off = (unsigned)(row * 128 + kk * 64 + l4 * 16) ^ (unsigned)((row & 7) << 4);
                bfr[ni] = *(const bf16x8*)((char*)Bs + off);
            }
#pragma unroll
            for (int mi = 0; mi < 4; ++mi)
#pragma unroll
                for (int ni = 0; ni < 4; ++ni)
                    acc[mi][ni] = __builtin_amdgcn_mfma_f32_16x16x32_bf16(
                        af[mi], bfr[ni], acc[mi][ni], 0, 0, 0);
        }
    }

    // epilogue: + bias, bf16 store. D-frag: col = l15, rows = l4*4 + r
#pragma unroll
    for (int ni = 0; ni < 4; ++ni) {
        int col = bn * 128 + wcol + ni * 16 + l15;
        float bv = bias[col];
#pragma unroll
        for (int mi = 0; mi < 4; ++mi) {
            int row0 = bm * 128 + wrow + mi * 16 + l4 * 4;
#pragma unroll
            for (int r = 0; r < 4; ++r)
                Y[(size_t)(row0 + r) * KDIM + col] = f2bf(acc[mi][ni][r] + bv);
        }
    }
}

// ---------------- Pass 1 (plan B fallback): fp32 in, convert in-loop ----------
__global__ __launch_bounds__(256)
void proj_gemm(const float* __restrict__ X, const float* __restrict__ W,
               const float* __restrict__ bias, u16* __restrict__ Y)
{
    __shared__ u16 As[128 * 64];
    __shared__ u16 Bs[128 * 64];

    int bx = blockIdx.x;
    int wg = (bx & 7) * 512 + (bx >> 3);
    int bm = wg >> 3;
    int bn = wg & 7;

    int tid  = threadIdx.x;
    int lane = tid & 63;
    int wid  = tid >> 6;
    int wrow = (wid >> 1) * 64;
    int wcol = (wid & 1) * 64;
    int l15 = lane & 15;
    int l4  = lane >> 4;

    int srow = tid >> 4;
    int scol = (tid & 15) * 4;

    const float* Xp = X + (size_t)bm * 128 * KDIM;
    const float* Wp = W + (size_t)bn * 128 * KDIM;

    f32x4 acc[4][4] = {};

    for (int k0 = 0; k0 < KDIM; k0 += 64) {
        __syncthreads();
#pragma unroll
        for (int r = 0; r < 8; ++r) {
            int row = r * 16 + srow;
            vfloat4 a = *(const vfloat4*)(Xp + (size_t)row * KDIM + k0 + scol);
            vfloat4 b = *(const vfloat4*)(Wp + (size_t)row * KDIM + k0 + scol);
            ushort4v ap, bp;
#pragma unroll
            for (int j = 0; j < 4; ++j) { ap[j] = f2bf(a[j]); bp[j] = f2bf(b[j]); }
            unsigned off = (unsigned)(row * 128 + scol * 2) ^ (unsigned)((row & 7) << 4);
            *(ushort4v*)((char*)As + off) = ap;
            *(ushort4v*)((char*)Bs + off) = bp;
        }
        __syncthreads();
#pragma unroll
        for (int kk = 0; kk < 2; ++kk) {
            bf16x8 af[4], bfr[4];
#pragma unroll
            for (int mi = 0; mi < 4; ++mi) {
                int row = wrow + mi * 16 + l15;
                unsigned off = (unsigned)(row * 128 + kk * 64 + l4 * 16) ^ (unsigned)((row & 7) << 4);
                af[mi] = *(const bf16x8*)((char*)As + off);
            }
#pragma unroll
            for (int ni = 0; ni < 4; ++ni) {
                int row = wcol + ni * 16 + l15;
                unsigned off = (unsigned)(row * 128 + kk * 64 + l4 * 16) ^ (unsigned)((row & 7) << 4);
                bfr[ni] = *(const bf16x8*)((char*)Bs + off);
            }
#pragma unroll
            for (int mi = 0; mi < 4; ++mi)
#pragma unroll
                for (int ni = 0; ni < 4; ++ni)
                    acc[mi][ni] = __builtin_amdgcn_mfma_f32_16x16x32_bf16(
                        af[mi], bfr[ni], acc[mi][ni], 0, 0, 0);
        }
    }

#pragma unroll
    for (int ni = 0; ni < 4; ++ni) {
        int col = bn * 128 + wcol + ni * 16 + l15;
        float bv = bias[col];
#pragma unroll
        for (int mi = 0; mi < 4; ++mi) {
            int row0 = bm * 128 + wrow + mi * 16 + l4 * 4;
#pragma unroll
            for (int r = 0; r < 4; ++r)
                Y[(size_t)(row0 + r) * KDIM + col] = f2bf(acc[mi][ni][r] + bv);
        }
    }
}

// ---------------- Pass 2: grouped attention ----------------
__global__ __launch_bounds__(256)
void attn_kernel(const u16* __restrict__ Qg, const u16* __restrict__ Kg,
                 const u16* __restrict__ Vg, float* __restrict__ Out)
{
    __shared__ u16 Qs[128 * 64];     // [q][d] swizzled
    __shared__ u16 KVs[64 * 136];    // union: Ks [128][64] swizzled / Vt [64][136]
    __shared__ u16 Ps[128 * 136];    // [q][k], row stride 136

    int g = blockIdx.x >> 4;
    int h = blockIdx.x & 15;

    int tid  = threadIdx.x;
    int lane = tid & 63;
    int wid  = tid >> 6;
    int l15 = lane & 15, l4 = lane >> 4;
    int qbase = wid * 32;

    size_t rowbase = (size_t)g * 128 * 1024 + (size_t)h * 64;

    {
        int r  = tid >> 1;
        int c0 = (tid & 1) * 32;
        const u16* qsrc = Qg + rowbase + (size_t)r * 1024 + c0;
        const u16* ksrc = Kg + rowbase + (size_t)r * 1024 + c0;
#pragma unroll
        for (int i = 0; i < 4; ++i) {
            ushort8v qv = *(const ushort8v*)(qsrc + i * 8);
            ushort8v kv = *(const ushort8v*)(ksrc + i * 8);
            unsigned off = (unsigned)(r * 128 + (c0 + i * 8) * 2) ^ (unsigned)((r & 7) << 4);
            *(ushort8v*)((char*)Qs + off) = qv;
            *(ushort8v*)((char*)KVs + off) = kv;
        }
    }
    __syncthreads();

    f32x4 st[8][2] = {};
#pragma unroll
    for (int kk = 0; kk < 2; ++kk) {
        bf16x8 kf[8];
#pragma unroll
        for (int mi = 0; mi < 8; ++mi) {
            int row = mi * 16 + l15;
            unsigned off = (unsigned)(row * 128 + kk * 64 + l4 * 16) ^ (unsigned)((row & 7) << 4);
            kf[mi] = *(const bf16x8*)((char*)KVs + off);
        }
#pragma unroll
        for (int qi = 0; qi < 2; ++qi) {
            int row = qbase + qi * 16 + l15;
            unsigned off = (unsigned)(row * 128 + kk * 64 + l4 * 16) ^ (unsigned)((row & 7) << 4);
            bf16x8 qf = *(const bf16x8*)((char*)Qs + off);
#pragma unroll
            for (int mi = 0; mi < 8; ++mi)
                st[mi][qi] = __builtin_amdgcn_mfma_f32_16x16x32_bf16(kf[mi], qf, st[mi][qi], 0, 0, 0);
        }
    }
    __syncthreads();

    {
        int r  = tid >> 1;
        int c0 = (tid & 1) * 32;
        const u16* vsrc = Vg + rowbase + (size_t)r * 1024 + c0;
#pragma unroll
        for (int i = 0; i < 4; ++i) {
            ushort8v vv = *(const ushort8v*)(vsrc + i * 8);
#pragma unroll
            for (int e = 0; e < 8; ++e)
                KVs[(c0 + i * 8 + e) * 136 + r] = vv[e];
        }
    }

    const float cexp = 0.125f * 1.44269504088896f;
#pragma unroll
    for (int qi = 0; qi < 2; ++qi) {
        float m = -3.0e38f;
#pragma unroll
        for (int mi = 0; mi < 8; ++mi)
#pragma unroll
            for (int r = 0; r < 4; ++r) m = fmaxf(m, st[mi][qi][r]);
        m = fmaxf(m, __shfl_xor(m, 16));
        m = fmaxf(m, __shfl_xor(m, 32));
        float s = 0.f;
#pragma unroll
        for (int mi = 0; mi < 8; ++mi)
#pragma unroll
            for (int r = 0; r < 4; ++r) {
                float p = exp2f((st[mi][qi][r] - m) * cexp);
                st[mi][qi][r] = p;
                s += p;
            }
        s += __shfl_xor(s, 16);
        s += __shfl_xor(s, 32);
        float inv = 1.0f / s;
        int q = qbase + qi * 16 + l15;
#pragma unroll
        for (int mi = 0; mi < 8; ++mi) {
            ushort4v pp;
#pragma unroll
            for (int r = 0; r < 4; ++r) pp[r] = f2bf(st[mi][qi][r] * inv);
            *(ushort4v*)((char*)Ps + (unsigned)(q * 272 + mi * 32 + l4 * 8)) = pp;
        }
    }
    __syncthreads();

    f32x4 o[2][4] = {};
#pragma unroll
    for (int kk = 0; kk < 4; ++kk) {
        bf16x8 pa[2];
#pragma unroll
        for (int mf = 0; mf < 2; ++mf) {
            int q = qbase + mf * 16 + l15;
            pa[mf] = *(const bf16x8*)((char*)Ps + (unsigned)(q * 272 + kk * 64 + l4 * 16));
        }
#pragma unroll
        for (int nf = 0; nf < 4; ++nf) {
            int d = nf * 16 + l15;
            bf16x8 vb = *(const bf16x8*)((char*)KVs + (unsigned)(d * 272 + kk * 64 + l4 * 16));
#pragma unroll
            for (int mf = 0; mf < 2; ++mf)
                o[mf][nf] = __builtin_amdgcn_mfma_f32_16x16x32_bf16(pa[mf], vb, o[mf][nf], 0, 0, 0);
        }
    }

#pragma unroll
    for (int mf = 0; mf < 2; ++mf)
#pragma unroll
        for (int nf = 0; nf < 4; ++nf) {
            int d  = nf * 16 + l15;
            int q0 = qbase + mf * 16 + l4 * 4;
#pragma unroll
            for (int r = 0; r < 4; ++r)
                Out[(size_t)(g * 128 + q0 + r) * 1024 + h * 64 + d] = o[mf][nf][r];
        }
}

extern "C" void kernel_launch(void* const* d_in, const int* in_sizes, int n_in,
                              void* d_out, int out_size, void* d_ws, size_t ws_size,
                              hipStream_t stream)
{
    const float* Xq = (const float*)d_in[0];
    const float* Xk = (const float*)d_in[1];
    const float* Xv = (const float*)d_in[2];
    const float* Wq = (const float*)d_in[3];
    const float* bq = (const float*)d_in[4];
    const float* Wk = (const float*)d_in[5];
    const float* bk = (const float*)d_in[6];
    const float* Wv = (const float*)d_in[7];
    const float* bv = (const float*)d_in[8];

    const size_t NE = (size_t)NROW * KDIM;       // 67,108,864
    const size_t WE = (size_t)KDIM * KDIM;       // 1,048,576

    u16* Qw = (u16*)d_ws;
    u16* Kw = Qw + NE;
    u16* Vw = Kw + NE;

    size_t need = NE * 2 * 3 + NE * 2 + WE * 2 * 3;  // QKV + X-stage + 3 W

    if (ws_size >= need) {
        u16* Xb  = Vw + NE;          // shared X staging buffer (reused 3x)
        u16* Wb0 = Xb + NE;
        u16* Wb1 = Wb0 + WE;
        u16* Wb2 = Wb1 + WE;

        cvt_f32_bf16<<<dim3(512),  dim3(256), 0, stream>>>(Wq, Wb0, (unsigned)(WE / 8));
        cvt_f32_bf16<<<dim3(512),  dim3(256), 0, stream>>>(Wk, Wb1, (unsigned)(WE / 8));
        cvt_f32_bf16<<<dim3(512),  dim3(256), 0, stream>>>(Wv, Wb2, (unsigned)(WE / 8));

        cvt_f32_bf16<<<dim3(2048), dim3(256), 0, stream>>>(Xq, Xb, (unsigned)(NE / 8));
        proj_gemm_bf16<<<dim3(4096), dim3(256), 0, stream>>>(Xb, Wb0, bq, Qw);
        cvt_f32_bf16<<<dim3(2048), dim3(256), 0, stream>>>(Xk, Xb, (unsigned)(NE / 8));
        proj_gemm_bf16<<<dim3(4096), dim3(256), 0, stream>>>(Xb, Wb1, bk, Kw);
        cvt_f32_bf16<<<dim3(2048), dim3(256), 0, stream>>>(Xv, Xb, (unsigned)(NE / 8));
        proj_gemm_bf16<<<dim3(4096), dim3(256), 0, stream>>>(Xb, Wb2, bv, Vw);
    } else {
        proj_gemm<<<dim3(4096), dim3(256), 0, stream>>>(Xq, Wq, bq, Qw);
        proj_gemm<<<dim3(4096), dim3(256), 0, stream>>>(Xk, Wk, bk, Kw);
        proj_gemm<<<dim3(4096), dim3(256), 0, stream>>>(Xv, Wv, bv, Vw);
    }

    attn_kernel<<<dim3(512 * 16), dim3(256), 0, stream>>>(Qw, Kw, Vw, (float*)d_out);
}

// Round 4
// 896.859 us; speedup vs baseline: 1.2397x; 1.1488x over previous
//
#include <hip/hip_runtime.h>
#include <hip/hip_bf16.h>

typedef unsigned short u16;
typedef __attribute__((ext_vector_type(8))) short bf16x8;
typedef __attribute__((ext_vector_type(4))) float f32x4;
typedef __attribute__((ext_vector_type(4))) float vfloat4;
typedef __attribute__((ext_vector_type(4))) unsigned short ushort4v;
typedef __attribute__((ext_vector_type(8))) unsigned short ushort8v;

#define DEV __device__ __forceinline__
#define AS1 __attribute__((address_space(1)))
#define AS3 __attribute__((address_space(3)))

DEV u16 f2bf(float f) {
    union { float f; unsigned u; } v; v.f = f;
    unsigned r = v.u + 0x7FFFu + ((v.u >> 16) & 1u);
    return (u16)(r >> 16);
}

DEV void gload_lds16(const void* g, void* l) {
    __builtin_amdgcn_global_load_lds((const AS1 unsigned int*)g,
                                     (AS3 unsigned int*)l, 16, 0, 0);
}

static constexpr int KDIM = 1024;   // embed
static constexpr int NROW = 65536;  // B*S

// ---------------- fp32 -> bf16 convert (for the small W matrices) -----------
__global__ __launch_bounds__(256)
void cvt_f32_bf16(const float* __restrict__ src, u16* __restrict__ dst, unsigned n8)
{
    unsigned stride = gridDim.x * blockDim.x;
    for (unsigned i = blockIdx.x * blockDim.x + threadIdx.x; i < n8; i += stride) {
        size_t base = (size_t)i * 8;
        vfloat4 a = *(const vfloat4*)(src + base);
        vfloat4 b = *(const vfloat4*)(src + base + 4);
        ushort8v o;
#pragma unroll
        for (int j = 0; j < 4; ++j) { o[j] = f2bf(a[j]); o[j + 4] = f2bf(b[j]); }
        *(ushort8v*)(dst + base) = o;
    }
}

// ---------------- Fused projection GEMM: Y = f2bf(X) @ Wb^T + b -------------
// 256x256 tile, BK=64, 8 waves (2Mx4N), per-wave 128x64 output.
// A (X, fp32): reg-staged early-issue, cvt+swizzled ds_write late (T14).
// B (W, bf16): global_load_lds with pre-swizzled source (rule #21).
// Double-buffered by K-tile parity; ONE barrier per iter (T3 minimum).
__global__ __launch_bounds__(512, 2)
void proj_gemm_fused(const float* __restrict__ X, const u16* __restrict__ W,
                     const float* __restrict__ bias, u16* __restrict__ Y)
{
    __shared__ u16 As[2][256 * 64];   // 32 KiB each, XOR-swizzled contents
    __shared__ u16 Bs[2][256 * 64];   // 128 KiB total

    int bx = blockIdx.x;                  // 0..1023
    int wg = (bx & 7) * 128 + (bx >> 3);  // XCD-chunked swizzle (1024 % 8 == 0)
    int bm = wg >> 2;                     // 0..255
    int bn = wg & 3;                      // 0..3

    int tid  = threadIdx.x;
    int lane = tid & 63;
    int wid  = tid >> 6;       // 0..7
    int wm   = wid >> 2;       // 0..1
    int wn   = wid & 3;        // 0..3
    int l15  = lane & 15;
    int l4   = lane >> 4;

    const float* Xp = X + (size_t)bm * 256 * KDIM;
    const u16*   Wp = W + (size_t)bn * 256 * KDIM;

    // B staging (gload_lds): issue j covers rows j*64 + (tid>>3); lane's col16
    // pre-swizzled with row so linear LDS dest holds swizzled layout.
    int brow_in = tid >> 3;                       // 0..63
    int bcol16s = (tid & 7) ^ (brow_in & 7);      // pre-swizzled source col16

    // A staging (regs): round ar covers rows ar*64 + (tid>>3), cols (tid&7)*8 fp32
    int arow_in = tid >> 3;
    int acol    = (tid & 7) * 8;

    f32x4 acc[8][4] = {};

    // ---- prologue: stage tile 0 into slot 0
    {
        vfloat4 areg[8];
#pragma unroll
        for (int ar = 0; ar < 4; ++ar) {
            const float* ga = Xp + (size_t)(ar * 64 + arow_in) * KDIM + acol;
            areg[2 * ar]     = *(const vfloat4*)ga;
            areg[2 * ar + 1] = *(const vfloat4*)(ga + 4);
        }
        const u16* wsrc = Wp + bcol16s * 8;
#pragma unroll
        for (int j = 0; j < 4; ++j)
            gload_lds16(wsrc + (size_t)(j * 64 + brow_in) * KDIM,
                        &Bs[0][(j * 64 + wid * 8) * 64]);
#pragma unroll
        for (int ar = 0; ar < 4; ++ar) {
            ushort8v o;
#pragma unroll
            for (int j2 = 0; j2 < 4; ++j2) {
                o[j2]     = f2bf(areg[2 * ar][j2]);
                o[j2 + 4] = f2bf(areg[2 * ar + 1][j2]);
            }
            int row = ar * 64 + arow_in;
            unsigned off = (unsigned)(row * 128 + (tid & 7) * 16) ^ (unsigned)((row & 7) << 4);
            *(ushort8v*)((char*)As[0] + off) = o;
        }
    }
    __syncthreads();

    // ---- main loop over 16 K-tiles
    for (int t = 0; t < 16; ++t) {
        int s = t & 1;
        vfloat4 areg[8];
        if (t < 15) {
            int k0n = (t + 1) * 64;
            // A loads first (their vmcnt wait at cvt leaves B's loads in flight)
#pragma unroll
            for (int ar = 0; ar < 4; ++ar) {
                const float* ga = Xp + (size_t)(ar * 64 + arow_in) * KDIM + k0n + acol;
                areg[2 * ar]     = *(const vfloat4*)ga;
                areg[2 * ar + 1] = *(const vfloat4*)(ga + 4);
            }
            const u16* wsrc = Wp + k0n + bcol16s * 8;
#pragma unroll
            for (int j = 0; j < 4; ++j)
                gload_lds16(wsrc + (size_t)(j * 64 + brow_in) * KDIM,
                            &Bs[s ^ 1][(j * 64 + wid * 8) * 64]);
        }
        __builtin_amdgcn_sched_barrier(0);   // pin issues above compute

        const u16* Ac = As[s];
        const u16* Bc = Bs[s];
#pragma unroll
        for (int kk = 0; kk < 2; ++kk) {
            bf16x8 af[8];
#pragma unroll
            for (int mi = 0; mi < 8; ++mi) {
                int row = wm * 128 + mi * 16 + l15;
                unsigned off = (unsigned)(row * 128 + kk * 64 + l4 * 16) ^ (unsigned)((row & 7) << 4);
                af[mi] = *(const bf16x8*)((const char*)Ac + off);
            }
            {
                int r0 = wn * 64 + l15;
                int r1 = wn * 64 + 16 + l15;
                bf16x8 bf0 = *(const bf16x8*)((const char*)Bc +
                    ((unsigned)(r0 * 128 + kk * 64 + l4 * 16) ^ (unsigned)((r0 & 7) << 4)));
                bf16x8 bf1 = *(const bf16x8*)((const char*)Bc +
                    ((unsigned)(r1 * 128 + kk * 64 + l4 * 16) ^ (unsigned)((r1 & 7) << 4)));
                __builtin_amdgcn_s_setprio(1);
#pragma unroll
                for (int mi = 0; mi < 8; ++mi) {
                    acc[mi][0] = __builtin_amdgcn_mfma_f32_16x16x32_bf16(af[mi], bf0, acc[mi][0], 0, 0, 0);
                    acc[mi][1] = __builtin_amdgcn_mfma_f32_16x16x32_bf16(af[mi], bf1, acc[mi][1], 0, 0, 0);
                }
                __builtin_amdgcn_s_setprio(0);
            }
            {
                int r2 = wn * 64 + 32 + l15;
                int r3 = wn * 64 + 48 + l15;
                bf16x8 bf2 = *(const bf16x8*)((const char*)Bc +
                    ((unsigned)(r2 * 128 + kk * 64 + l4 * 16) ^ (unsigned)((r2 & 7) << 4)));
                bf16x8 bf3 = *(const bf16x8*)((const char*)Bc +
                    ((unsigned)(r3 * 128 + kk * 64 + l4 * 16) ^ (unsigned)((r3 & 7) << 4)));
                __builtin_amdgcn_s_setprio(1);
#pragma unroll
                for (int mi = 0; mi < 8; ++mi) {
                    acc[mi][2] = __builtin_amdgcn_mfma_f32_16x16x32_bf16(af[mi], bf2, acc[mi][2], 0, 0, 0);
                    acc[mi][3] = __builtin_amdgcn_mfma_f32_16x16x32_bf16(af[mi], bf3, acc[mi][3], 0, 0, 0);
                }
                __builtin_amdgcn_s_setprio(0);
            }
        }
        __builtin_amdgcn_sched_barrier(0);   // keep cvt/write below compute

        if (t < 15) {
            // write-late: A regs -> bf16 -> swizzled LDS (slot s^1)
#pragma unroll
            for (int ar = 0; ar < 4; ++ar) {
                ushort8v o;
#pragma unroll
                for (int j2 = 0; j2 < 4; ++j2) {
                    o[j2]     = f2bf(areg[2 * ar][j2]);
                    o[j2 + 4] = f2bf(areg[2 * ar + 1][j2]);
                }
                int row = ar * 64 + arow_in;
                unsigned off = (unsigned)(row * 128 + (tid & 7) * 16) ^ (unsigned)((row & 7) << 4);
                *(ushort8v*)((char*)As[s ^ 1] + off) = o;
            }
        }
        __syncthreads();   // drains vmcnt (B gload) + lgkm (A ds_write)
    }

    // ---- epilogue: + bias, bf16 store. D-frag: col(N)=l15, rows(M)=l4*4+r
#pragma unroll
    for (int ni = 0; ni < 4; ++ni) {
        int col = bn * 256 + wn * 64 + ni * 16 + l15;
        float bv = bias[col];
#pragma unroll
        for (int mi = 0; mi < 8; ++mi) {
            int row0 = bm * 256 + wm * 128 + mi * 16 + l4 * 4;
#pragma unroll
            for (int r = 0; r < 4; ++r)
                Y[(size_t)(row0 + r) * KDIM + col] = f2bf(acc[mi][ni][r] + bv);
        }
    }
}

// ---------------- Fallback: fp32 in, convert in-loop (128^2, 2-barrier) -----
__global__ __launch_bounds__(256)
void proj_gemm(const float* __restrict__ X, const float* __restrict__ W,
               const float* __restrict__ bias, u16* __restrict__ Y)
{
    __shared__ u16 As[128 * 64];
    __shared__ u16 Bs[128 * 64];

    int bx = blockIdx.x;
    int wg = (bx & 7) * 512 + (bx >> 3);
    int bm = wg >> 3;
    int bn = wg & 7;

    int tid  = threadIdx.x;
    int lane = tid & 63;
    int wid  = tid >> 6;
    int wrow = (wid >> 1) * 64;
    int wcol = (wid & 1) * 64;
    int l15 = lane & 15;
    int l4  = lane >> 4;

    int srow = tid >> 4;
    int scol = (tid & 15) * 4;

    const float* Xp = X + (size_t)bm * 128 * KDIM;
    const float* Wp = W + (size_t)bn * 128 * KDIM;

    f32x4 acc[4][4] = {};

    for (int k0 = 0; k0 < KDIM; k0 += 64) {
        __syncthreads();
#pragma unroll
        for (int r = 0; r < 8; ++r) {
            int row = r * 16 + srow;
            vfloat4 a = *(const vfloat4*)(Xp + (size_t)row * KDIM + k0 + scol);
            vfloat4 b = *(const vfloat4*)(Wp + (size_t)row * KDIM + k0 + scol);
            ushort4v ap, bp;
#pragma unroll
            for (int j = 0; j < 4; ++j) { ap[j] = f2bf(a[j]); bp[j] = f2bf(b[j]); }
            unsigned off = (unsigned)(row * 128 + scol * 2) ^ (unsigned)((row & 7) << 4);
            *(ushort4v*)((char*)As + off) = ap;
            *(ushort4v*)((char*)Bs + off) = bp;
        }
        __syncthreads();
#pragma unroll
        for (int kk = 0; kk < 2; ++kk) {
            bf16x8 af[4], bfr[4];
#pragma unroll
            for (int mi = 0; mi < 4; ++mi) {
                int row = wrow + mi * 16 + l15;
                unsigned off = (unsigned)(row * 128 + kk * 64 + l4 * 16) ^ (unsigned)((row & 7) << 4);
                af[mi] = *(const bf16x8*)((char*)As + off);
            }
#pragma unroll
            for (int ni = 0; ni < 4; ++ni) {
                int row = wcol + ni * 16 + l15;
                unsigned off = (unsigned)(row * 128 + kk * 64 + l4 * 16) ^ (unsigned)((row & 7) << 4);
                bfr[ni] = *(const bf16x8*)((char*)Bs + off);
            }
#pragma unroll
            for (int mi = 0; mi < 4; ++mi)
#pragma unroll
                for (int ni = 0; ni < 4; ++ni)
                    acc[mi][ni] = __builtin_amdgcn_mfma_f32_16x16x32_bf16(
                        af[mi], bfr[ni], acc[mi][ni], 0, 0, 0);
        }
    }

#pragma unroll
    for (int ni = 0; ni < 4; ++ni) {
        int col = bn * 128 + wcol + ni * 16 + l15;
        float bv = bias[col];
#pragma unroll
        for (int mi = 0; mi < 4; ++mi) {
            int row0 = bm * 128 + wrow + mi * 16 + l4 * 4;
#pragma unroll
            for (int r = 0; r < 4; ++r)
                Y[(size_t)(row0 + r) * KDIM + col] = f2bf(acc[mi][ni][r] + bv);
        }
    }
}

// ---------------- Pass 2: grouped attention ----------------
__global__ __launch_bounds__(256)
void attn_kernel(const u16* __restrict__ Qg, const u16* __restrict__ Kg,
                 const u16* __restrict__ Vg, float* __restrict__ Out)
{
    __shared__ u16 Qs[128 * 64];     // [q][d] swizzled
    __shared__ u16 KVs[64 * 136];    // union: Ks [128][64] swizzled / Vt [64][136]
    __shared__ u16 Ps[128 * 136];    // [q][k], row stride 136

    int g = blockIdx.x >> 4;
    int h = blockIdx.x & 15;

    int tid  = threadIdx.x;
    int lane = tid & 63;
    int wid  = tid >> 6;
    int l15 = lane & 15, l4 = lane >> 4;
    int qbase = wid * 32;

    size_t rowbase = (size_t)g * 128 * 1024 + (size_t)h * 64;

    {
        int r  = tid >> 1;
        int c0 = (tid & 1) * 32;
        const u16* qsrc = Qg + rowbase + (size_t)r * 1024 + c0;
        const u16* ksrc = Kg + rowbase + (size_t)r * 1024 + c0;
#pragma unroll
        for (int i = 0; i < 4; ++i) {
            ushort8v qv = *(const ushort8v*)(qsrc + i * 8);
            ushort8v kv = *(const ushort8v*)(ksrc + i * 8);
            unsigned off = (unsigned)(r * 128 + (c0 + i * 8) * 2) ^ (unsigned)((r & 7) << 4);
            *(ushort8v*)((char*)Qs + off) = qv;
            *(ushort8v*)((char*)KVs + off) = kv;
        }
    }
    __syncthreads();

    f32x4 st[8][2] = {};
#pragma unroll
    for (int kk = 0; kk < 2; ++kk) {
        bf16x8 kf[8];
#pragma unroll
        for (int mi = 0; mi < 8; ++mi) {
            int row = mi * 16 + l15;
            unsigned off = (unsigned)(row * 128 + kk * 64 + l4 * 16) ^ (unsigned)((row & 7) << 4);
            kf[mi] = *(const bf16x8*)((char*)KVs + off);
        }
#pragma unroll
        for (int qi = 0; qi < 2; ++qi) {
            int row = qbase + qi * 16 + l15;
            unsigned off = (unsigned)(row * 128 + kk * 64 + l4 * 16) ^ (unsigned)((row & 7) << 4);
            bf16x8 qf = *(const bf16x8*)((char*)Qs + off);
#pragma unroll
            for (int mi = 0; mi < 8; ++mi)
                st[mi][qi] = __builtin_amdgcn_mfma_f32_16x16x32_bf16(kf[mi], qf, st[mi][qi], 0, 0, 0);
        }
    }
    __syncthreads();

    {
        int r  = tid >> 1;
        int c0 = (tid & 1) * 32;
        const u16* vsrc = Vg + rowbase + (size_t)r * 1024 + c0;
#pragma unroll
        for (int i = 0; i < 4; ++i) {
            ushort8v vv = *(const ushort8v*)(vsrc + i * 8);
#pragma unroll
            for (int e = 0; e < 8; ++e)
                KVs[(c0 + i * 8 + e) * 136 + r] = vv[e];
        }
    }

    const float cexp = 0.125f * 1.44269504088896f;
#pragma unroll
    for (int qi = 0; qi < 2; ++qi) {
        float m = -3.0e38f;
#pragma unroll
        for (int mi = 0; mi < 8; ++mi)
#pragma unroll
            for (int r = 0; r < 4; ++r) m = fmaxf(m, st[mi][qi][r]);
        m = fmaxf(m, __shfl_xor(m, 16));
        m = fmaxf(m, __shfl_xor(m, 32));
        float s = 0.f;
#pragma unroll
        for (int mi = 0; mi < 8; ++mi)
#pragma unroll
            for (int r = 0; r < 4; ++r) {
                float p = exp2f((st[mi][qi][r] - m) * cexp);
                st[mi][qi][r] = p;
                s += p;
            }
        s += __shfl_xor(s, 16);
        s += __shfl_xor(s, 32);
        float inv = 1.0f / s;
        int q = qbase + qi * 16 + l15;
#pragma unroll
        for (int mi = 0; mi < 8; ++mi) {
            ushort4v pp;
#pragma unroll
            for (int r = 0; r < 4; ++r) pp[r] = f2bf(st[mi][qi][r] * inv);
            *(ushort4v*)((char*)Ps + (unsigned)(q * 272 + mi * 32 + l4 * 8)) = pp;
        }
    }
    __syncthreads();

    f32x4 o[2][4] = {};
#pragma unroll
    for (int kk = 0; kk < 4; ++kk) {
        bf16x8 pa[2];
#pragma unroll
        for (int mf = 0; mf < 2; ++mf) {
            int q = qbase + mf * 16 + l15;
            pa[mf] = *(const bf16x8*)((char*)Ps + (unsigned)(q * 272 + kk * 64 + l4 * 16));
        }
#pragma unroll
        for (int nf = 0; nf < 4; ++nf) {
            int d = nf * 16 + l15;
            bf16x8 vb = *(const bf16x8*)((char*)KVs + (unsigned)(d * 272 + kk * 64 + l4 * 16));
#pragma unroll
            for (int mf = 0; mf < 2; ++mf)
                o[mf][nf] = __builtin_amdgcn_mfma_f32_16x16x32_bf16(pa[mf], vb, o[mf][nf], 0, 0, 0);
        }
    }

#pragma unroll
    for (int mf = 0; mf < 2; ++mf)
#pragma unroll
        for (int nf = 0; nf < 4; ++nf) {
            int d  = nf * 16 + l15;
            int q0 = qbase + mf * 16 + l4 * 4;
#pragma unroll
            for (int r = 0; r < 4; ++r)
                Out[(size_t)(g * 128 + q0 + r) * 1024 + h * 64 + d] = o[mf][nf][r];
        }
}

extern "C" void kernel_launch(void* const* d_in, const int* in_sizes, int n_in,
                              void* d_out, int out_size, void* d_ws, size_t ws_size,
                              hipStream_t stream)
{
    const float* Xq = (const float*)d_in[0];
    const float* Xk = (const float*)d_in[1];
    const float* Xv = (const float*)d_in[2];
    const float* Wq = (const float*)d_in[3];
    const float* bq = (const float*)d_in[4];
    const float* Wk = (const float*)d_in[5];
    const float* bk = (const float*)d_in[6];
    const float* Wv = (const float*)d_in[7];
    const float* bv = (const float*)d_in[8];

    const size_t NE = (size_t)NROW * KDIM;       // 67,108,864
    const size_t WE = (size_t)KDIM * KDIM;       // 1,048,576

    u16* Qw = (u16*)d_ws;
    u16* Kw = Qw + NE;
    u16* Vw = Kw + NE;

    size_t need = NE * 2 * 3 + WE * 2 * 3;       // QKV bf16 + 3 W bf16

    if (ws_size >= need) {
        u16* Wb0 = Vw + NE;
        u16* Wb1 = Wb0 + WE;
        u16* Wb2 = Wb1 + WE;

        cvt_f32_bf16<<<dim3(512), dim3(256), 0, stream>>>(Wq, Wb0, (unsigned)(WE / 8));
        cvt_f32_bf16<<<dim3(512), dim3(256), 0, stream>>>(Wk, Wb1, (unsigned)(WE / 8));
        cvt_f32_bf16<<<dim3(512), dim3(256), 0, stream>>>(Wv, Wb2, (unsigned)(WE / 8));

        proj_gemm_fused<<<dim3(1024), dim3(512), 0, stream>>>(Xq, Wb0, bq, Qw);
        proj_gemm_fused<<<dim3(1024), dim3(512), 0, stream>>>(Xk, Wb1, bk, Kw);
        proj_gemm_fused<<<dim3(1024), dim3(512), 0, stream>>>(Xv, Wb2, bv, Vw);
    } else {
        proj_gemm<<<dim3(4096), dim3(256), 0, stream>>>(Xq, Wq, bq, Qw);
        proj_gemm<<<dim3(4096), dim3(256), 0, stream>>>(Xk, Wk, bk, Kw);
        proj_gemm<<<dim3(4096), dim3(256), 0, stream>>>(Xv, Wv, bv, Vw);
    }

    attn_kernel<<<dim3(512 * 16), dim3(256), 0, stream>>>(Qw, Kw, Vw, (float*)d_out);
}